// Round 9
// baseline (225.081 us; speedup 1.0000x reference)
//
#include <hip/hip_runtime.h>
#include <math.h>
#include <stddef.h>

#define HQ   16
#define HKV  8
#define DH   128
#define HID  2048
#define CC   16384
#define NCH  128            // flash chunks of 128: 128*128 = 16384 = CC
#define CHUNK 128

// d_out layout (FLOAT32, 4096 elements): [attn 2048][k_new 8*128][v 8*128]

// ---- K1: QKV projections. One wave per output element.
__global__ __launch_bounds__(256, 4)
void k_qkv(const float* __restrict__ x,
           const float* __restrict__ Wq,
           const float* __restrict__ Wk,
           const float* __restrict__ Wv,
           float* __restrict__ raw){
  int wave = threadIdx.x >> 6, lane = threadIdx.x & 63;
  int e = blockIdx.x * 4 + wave;
  const float* W;
  if (e < 2048)      W = Wq + (size_t)e * HID;
  else if (e < 3072) W = Wk + (size_t)(e - 2048) * HID;
  else               W = Wv + (size_t)(e - 3072) * HID;
  float acc = 0.f;
  #pragma unroll
  for (int j = 0; j < 4; ++j){
    int base = (j * 64 + lane) * 8;
    float4 a0 = *(const float4*)(x + base);
    float4 a1 = *(const float4*)(x + base + 4);
    float4 b0 = *(const float4*)(W + base);
    float4 b1 = *(const float4*)(W + base + 4);
    acc += a0.x*b0.x + a0.y*b0.y + a0.z*b0.z + a0.w*b0.w
         + a1.x*b1.x + a1.y*b1.y + a1.z*b1.z + a1.w*b1.w;
  }
  #pragma unroll
  for (int off = 32; off; off >>= 1) acc += __shfl_down(acc, off, 64);
  if (lane == 0) raw[e] = acc;
}

// ---- K2: RMSNorm + RoPE (q,k), v passthrough.
__global__ void k_normrope(const float* __restrict__ raw,
                           const float* __restrict__ cosb,
                           const float* __restrict__ sinb,
                           const float* __restrict__ qw,
                           const float* __restrict__ kw,
                           float* __restrict__ qf,
                           float* __restrict__ kf,
                           float* __restrict__ out){
  __shared__ float lds[DH];
  __shared__ float wsum[2];
  int b = blockIdx.x, t = threadIdx.x;
  if (b >= 24){  // v copy to d_out
    int h = b - 24;
    out[3072 + h * DH + t] = raw[3072 + h * DH + t];
    return;
  }
  bool isq = (b < 16);
  int h = isq ? b : b - 16;
  float val = isq ? raw[h * DH + t] : raw[2048 + h * DH + t];
  float ss = val * val;
  #pragma unroll
  for (int off = 32; off; off >>= 1) ss += __shfl_down(ss, off, 64);
  if ((t & 63) == 0) wsum[t >> 6] = ss;
  __syncthreads();
  float rms = sqrtf((wsum[0] + wsum[1]) / 128.f + 1e-6f);
  float w = isq ? qw[t] : kw[t];
  float normed = val / rms * w;
  lds[t] = normed;
  __syncthreads();
  float rot = (t < 64) ? -lds[t + 64] : lds[t - 64];
  float res = normed * cosb[t] + rot * sinb[t];
  if (isq) qf[h * DH + t] = res;
  else { kf[h * DH + t] = res; out[2048 + h * DH + t] = res; }
}

// ---- K3: fused flash-decode chunk kernel. grid = HKV*NCH = 1024 blocks, 512 thr.
// Max-occupancy version: 4 blocks/CU * 8 waves = 32 waves/CU.
__global__ __launch_bounds__(512, 8)
void k_flash(const float* __restrict__ qf,
             const float* __restrict__ kcache,  // [HKV][DH][CC]
             const float* __restrict__ vcache,  // [HKV][CC][DH]
             const float* __restrict__ mask,    // [CC+1]
             float* __restrict__ opart,         // [HQ][NCH][DH]
             float2* __restrict__ ml){          // [HQ][NCH]
  __shared__ float q_s[2][DH];
  __shared__ float sc_part[8][2][CHUNK];   // d-group partial dots (8 KB)
  __shared__ float p_s[2][CHUNK];
  __shared__ float part[2][16][DH];        // 16 KB
  __shared__ float red[8];
  int kv = blockIdx.x >> 7, ch = blockIdx.x & 127;
  int c0 = ch << 7;
  int t = threadIdx.x;
  if (t < 256) q_s[t >> 7][t & 127] = qf[(kv * 2 + (t >> 7)) * DH + (t & 127)];
  __syncthreads();
  const float scale = 0.08838834764831845f;  // 128^-0.5

  // ---- Phase A: QK^T. Thread (dg, ln): dg in [0,8) owns 16 dims; ln owns 2 positions.
  {
    int dg = t >> 6, ln = t & 63;
    const float* kp = kcache + (size_t)kv * DH * CC + (size_t)(dg * 16) * CC + (c0 + ln * 2);
    float a00 = 0.f, a01 = 0.f, a10 = 0.f, a11 = 0.f;
    #pragma unroll
    for (int dd = 0; dd < 16; ++dd){
      float2 kk = *(const float2*)(kp + (size_t)dd * CC);
      float q0 = q_s[0][dg * 16 + dd], q1 = q_s[1][dg * 16 + dd];
      a00 += q0 * kk.x; a01 += q0 * kk.y;
      a10 += q1 * kk.x; a11 += q1 * kk.y;
    }
    *(float2*)&sc_part[dg][0][ln * 2] = make_float2(a00, a01);
    *(float2*)&sc_part[dg][1][ln * 2] = make_float2(a10, a11);
  }
  __syncthreads();

  // ---- Phase B: combine partials, chunk softmax. Threads 0..255: (h = t>>7, p = t&127).
  // Waves 0-1 own head0, waves 2-3 own head1.
  float s_val = 0.f;
  int hB = t >> 7, pB = t & 127;
  int wv = t >> 6, ln = t & 63;
  if (t < 256){
    float sum8 = 0.f;
    #pragma unroll
    for (int dg = 0; dg < 8; ++dg) sum8 += sc_part[dg][hB][pB];
    s_val = sum8 * scale + mask[c0 + pB];
    float lmax = s_val;
    #pragma unroll
    for (int off = 32; off; off >>= 1) lmax = fmaxf(lmax, __shfl_down(lmax, off, 64));
    if (ln == 0) red[wv] = lmax;
  }
  __syncthreads();
  float m0 = fmaxf(red[0], red[1]);
  float m1 = fmaxf(red[2], red[3]);
  float pe = 0.f;
  if (t < 256){
    pe = __expf(s_val - (hB ? m1 : m0));
    p_s[hB][pB] = pe;
    #pragma unroll
    for (int off = 32; off; off >>= 1) pe += __shfl_down(pe, off, 64);
  }
  __syncthreads();               // all reads of red done; p_s visible after next sync
  if (t < 256 && ln == 0) red[wv] = pe;
  __syncthreads();
  if (t == 0){
    ml[(size_t)(kv * 2)     * NCH + ch] = make_float2(m0, red[0] + red[1]);
    ml[(size_t)(kv * 2 + 1) * NCH + ch] = make_float2(m1, red[2] + red[3]);
  }

  // ---- Phase C: partial O. 16 slices x 32 dim-threads (float4), 8 iters.
  {
    int s = t >> 5, d4 = (t & 31) * 4;
    const float* vbase = vcache + (size_t)kv * CC * DH + d4;
    float4 a0 = make_float4(0.f, 0.f, 0.f, 0.f);
    float4 a1 = make_float4(0.f, 0.f, 0.f, 0.f);
    #pragma unroll
    for (int i = 0; i < 8; ++i){
      int off = i * 16 + s;
      float pp0 = p_s[0][off];
      float pp1 = p_s[1][off];
      float4 v = *(const float4*)(vbase + (size_t)(c0 + off) * DH);
      a0.x += pp0 * v.x; a0.y += pp0 * v.y; a0.z += pp0 * v.z; a0.w += pp0 * v.w;
      a1.x += pp1 * v.x; a1.y += pp1 * v.y; a1.z += pp1 * v.z; a1.w += pp1 * v.w;
    }
    *(float4*)&part[0][s][d4] = a0;
    *(float4*)&part[1][s][d4] = a1;
  }
  __syncthreads();
  if (t < 256){
    int hh = t >> 7, d = t & 127;
    float o = 0.f;
    #pragma unroll
    for (int ss = 0; ss < 16; ++ss) o += part[hh][ss][d];
    int qh = kv * 2 + hh;
    opart[((size_t)qh * NCH + ch) * DH + d] = o;
  }
}

// ---- K4: combine chunk partials + new-token term -> attn_in. grid=HQ, 128 threads.
__global__ void k_combine(const float* __restrict__ opart,
                          const float2* __restrict__ ml,
                          const float* __restrict__ qf,
                          const float* __restrict__ kf,
                          const float* __restrict__ vnew,   // raw+3072: [HKV][DH]
                          const float* __restrict__ mask,
                          float* __restrict__ attn_in){
  __shared__ float red[2];
  int qh = blockIdx.x, d = threadIdx.x;
  int kv = qh >> 1;
  float M = -1e30f;
  #pragma unroll 8
  for (int ch = 0; ch < NCH; ++ch) M = fmaxf(M, ml[(size_t)qh * NCH + ch].x);
  float o = 0.f, L = 0.f;
  for (int ch = 0; ch < NCH; ++ch){
    float2 m = ml[(size_t)qh * NCH + ch];
    float w = __expf(m.x - M);
    L += m.y * w;
    o += w * opart[((size_t)qh * NCH + ch) * DH + d];
  }
  float prod = qf[qh * DH + d] * kf[kv * DH + d];
  float sum = prod;
  #pragma unroll
  for (int off = 32; off; off >>= 1) sum += __shfl_down(sum, off, 64);
  if ((d & 63) == 0) red[d >> 6] = sum;
  __syncthreads();
  float s_new = (red[0] + red[1]) * 0.08838834764831845f + mask[CC];
  float pn = __expf(s_new - M);
  L += pn;
  o += pn * vnew[kv * DH + d];
  attn_in[qh * DH + d] = o / L;
}

// ---- K5: o_proj GEMV. One wave per output element.
__global__ __launch_bounds__(256, 4)
void k_oproj(const float* __restrict__ attn_in,
             const float* __restrict__ Wo,
             float* __restrict__ out){
  int wave = threadIdx.x >> 6, lane = threadIdx.x & 63;
  int e = blockIdx.x * 4 + wave;
  const float* W = Wo + (size_t)e * HID;
  float acc = 0.f;
  #pragma unroll
  for (int j = 0; j < 4; ++j){
    int base = (j * 64 + lane) * 8;
    float4 a0 = *(const float4*)(attn_in + base);
    float4 a1 = *(const float4*)(attn_in + base + 4);
    float4 b0 = *(const float4*)(W + base);
    float4 b1 = *(const float4*)(W + base + 4);
    acc += a0.x*b0.x + a0.y*b0.y + a0.z*b0.z + a0.w*b0.w
         + a1.x*b1.x + a1.y*b1.y + a1.z*b1.z + a1.w*b1.w;
  }
  #pragma unroll
  for (int off = 32; off; off >>= 1) acc += __shfl_down(acc, off, 64);
  if (lane == 0) out[e] = acc;
}

extern "C" void kernel_launch(void* const* d_in, const int* in_sizes, int n_in,
                              void* d_out, int out_size, void* d_ws, size_t ws_size,
                              hipStream_t stream){
  const float* x    = (const float*)d_in[0];
  const float* cosb = (const float*)d_in[1];
  const float* sinb = (const float*)d_in[2];
  const float* mask = (const float*)d_in[3];
  const float* kc   = (const float*)d_in[4];
  const float* vc   = (const float*)d_in[5];
  const float* Wq   = (const float*)d_in[6];
  const float* Wk   = (const float*)d_in[7];
  const float* Wv   = (const float*)d_in[8];
  const float* Wo   = (const float*)d_in[9];
  const float* qw   = (const float*)d_in[10];
  const float* kw   = (const float*)d_in[11];
  float* out = (float*)d_out;
  float* ws = (float*)d_ws;
  float* raw     = ws;                          // 4096
  float* qf      = ws + 4096;                   // 2048
  float* kf      = ws + 6144;                   // 1024
  float* opart   = ws + 8192;                   // 16*128*128 = 262144
  float2* ML     = (float2*)(ws + 270336);      // 16*128 float2 = 4096 floats
  float* attn_in = ws + 274432;                 // 2048

  k_qkv     <<<1024, 256, 0, stream>>>(x, Wq, Wk, Wv, raw);
  k_normrope<<<32,   128, 0, stream>>>(raw, cosb, sinb, qw, kw, qf, kf, out);
  k_flash   <<<HKV * NCH, 512, 0, stream>>>(qf, kc, vc, mask, opart, ML);
  k_combine <<<HQ, 128, 0, stream>>>(opart, ML, qf, kf, raw + 3072, mask, attn_in);
  k_oproj   <<<512, 256, 0, stream>>>(attn_in, Wo, out);
}